// Round 5
// baseline (461.349 us; speedup 1.0000x reference)
//
#include <hip/hip_runtime.h>
#include <math.h>

#define D 128
#define EPS 1e-6f
#define SKR_LD 136            // shorts per row, row-major sigma [32][D]
#define SKT_LD 40             // shorts per row, transposed sigma [D][32]
#define DV_LD  40             // shorts per row, dvT [D][32]
#define SKR_SZ (32 * SKR_LD)  // 4352 shorts (8704 B)
#define SKT_SZ (128 * SKT_LD) // 5120 shorts (10240 B)

typedef __attribute__((ext_vector_type(8))) short short8;
typedef __attribute__((ext_vector_type(4))) float f32x4;
typedef unsigned short ushort_t;
typedef unsigned long long u64;

__device__ __forceinline__ float elu1(float x) {
    float e = __expf(fminf(x, 0.f));
    return x > 0.f ? x + 1.f : e;
}
__device__ __forceinline__ unsigned short bf16rne(float f) {
    unsigned u = __builtin_bit_cast(unsigned, f);
    u += 0x7FFFu + ((u >> 16) & 1u);
    return (unsigned short)(u >> 16);
}
__device__ __forceinline__ u64 pack4(float a, float b, float c, float d) {
    return (u64)bf16rne(a) | ((u64)bf16rne(b) << 16) |
           ((u64)bf16rne(c) << 32) | ((u64)bf16rne(d) << 48);
}

// ---------------------------------------------------------------------------
// Update: per (bh, chunk): pM = sigma_k^T @ (V - (sigma_k@M)/(sigma_k@z+eps)),
// pz = sum_s sigma_k.  512 threads = 8 waves; wave w owns e-tile w.
// Single-buffered skR/skT (29.3 KB LDS) with 2 barriers per 32-row batch:
//   [MFMA1 -> delta_v -> dvT roundtrip -> MFMA2] barrier [STAGE(b+1)+norm] barrier
// Norm in fp32 via wave shuffle-reduce during STAGE (read one batch later).
// V(b+1) prefetched into registers. 3 blocks/CU target (launch_bounds 512,6).
// ---------------------------------------------------------------------------
__global__ __launch_bounds__(512, 6)
void k_update(const float* __restrict__ key, const float* __restrict__ value,
              const float* __restrict__ M, const float* __restrict__ z,
              float* __restrict__ pM, float* __restrict__ pz, int S)
{
    __shared__ alignas(16) ushort_t skR[SKR_SZ];
    __shared__ alignas(16) ushort_t skT[SKT_SZ];
    __shared__ alignas(16) ushort_t dvT[128 * DV_LD];
    __shared__ float normsh[32];

    const int t  = threadIdx.x;
    const int bh = blockIdx.x, ch = blockIdx.y, NCH = gridDim.y;
    const int SC = S / NCH, NB = SC / 32, s0g = ch * SC;

    const int w = t >> 6, g = (t >> 4) & 3, m = t & 15;  // compute roles
    const int c2 = t & 63;                               // stage: rows 4w..4w+3, cols 2c2,2c2+1

    const float* Kb = key   + (size_t)bh * S * D;
    const float* Vb = value + (size_t)bh * S * D;
    const float* Mb = M + (size_t)bh * D * D;
    const float* zb = z + (size_t)bh * D;

    // z (fp32, stage cols) for the shuffle-norm
    const float zr0 = zb[2 * c2], zr1 = zb[2 * c2 + 1];

    // M B-frags in registers (this wave's e-tile)
    short8 Bf[4];
    #pragma unroll
    for (int ks = 0; ks < 4; ++ks) {
        short8 f;
        #pragma unroll
        for (int j = 0; j < 8; ++j)
            f[j] = (short)bf16rne(Mb[(size_t)(32 * ks + 8 * g + j) * D + 16 * w + m]);
        Bf[ks] = f;
    }

    f32x4 acc[8];
    #pragma unroll
    for (int dt = 0; dt < 8; ++dt) acc[dt] = 0.f;
    float zacc0 = 0.f, zacc1 = 0.f;

    // stage: elu(K rows) -> skR (row-major) + skT (transposed); fp32 norm; z acc
    auto STAGE = [&](const float2* kr) {
        float sv0[4], sv1[4];
        #pragma unroll
        for (int i = 0; i < 4; ++i) { sv0[i] = elu1(kr[i].x); sv1[i] = elu1(kr[i].y); }
        #pragma unroll
        for (int i = 0; i < 4; ++i)
            *(unsigned*)&skR[(4 * w + i) * SKR_LD + 2 * c2] =
                (unsigned)bf16rne(sv0[i]) | ((unsigned)bf16rne(sv1[i]) << 16);
        *(u64*)&skT[(2 * c2) * SKT_LD + 4 * w]     = pack4(sv0[0], sv0[1], sv0[2], sv0[3]);
        *(u64*)&skT[(2 * c2 + 1) * SKT_LD + 4 * w] = pack4(sv1[0], sv1[1], sv1[2], sv1[3]);
        float p[4];
        #pragma unroll
        for (int i = 0; i < 4; ++i) {
            p[i] = sv0[i] * zr0 + sv1[i] * zr1;
            zacc0 += sv0[i]; zacc1 += sv1[i];
        }
        #pragma unroll
        for (int mask = 32; mask >= 1; mask >>= 1) {
            p[0] += __shfl_xor(p[0], mask, 64);
            p[1] += __shfl_xor(p[1], mask, 64);
            p[2] += __shfl_xor(p[2], mask, 64);
            p[3] += __shfl_xor(p[3], mask, 64);
        }
        int l = t & 63;
        if (l < 4) {
            float pv = l == 0 ? p[0] : l == 1 ? p[1] : l == 2 ? p[2] : p[3];
            normsh[4 * w + l] = pv + EPS;
        }
    };

    // prologue: stage batch 0; prefetch K(1), V(0)
    float2 kr[4];
    #pragma unroll
    for (int i = 0; i < 4; ++i)
        kr[i] = *(const float2*)&Kb[(size_t)(s0g + 4 * w + i) * D + 2 * c2];
    STAGE(kr);
    if (NB > 1) {
        #pragma unroll
        for (int i = 0; i < 4; ++i)
            kr[i] = *(const float2*)&Kb[(size_t)(s0g + 32 + 4 * w + i) * D + 2 * c2];
    }
    float vn[2][4];
    #pragma unroll
    for (int st = 0; st < 2; ++st)
        #pragma unroll
        for (int r = 0; r < 4; ++r)
            vn[st][r] = Vb[(size_t)(s0g + 16 * st + 4 * g + r) * D + 16 * w + m];
    __syncthreads();

    for (int b = 0; b < NB; ++b) {
        const int sbat = s0g + 32 * b;

        // current V from prefetch regs
        float vv[2][4];
        #pragma unroll
        for (int st = 0; st < 2; ++st)
            #pragma unroll
            for (int r = 0; r < 4; ++r) vv[st][r] = vn[st][r];

        // issue V(b+1) prefetch
        if (b + 1 < NB) {
            #pragma unroll
            for (int st = 0; st < 2; ++st)
                #pragma unroll
                for (int r = 0; r < 4; ++r)
                    vn[st][r] = Vb[(size_t)(sbat + 32 + 16 * st + 4 * g + r) * D + 16 * w + m];
        }

        // MFMA1: mem_pred = sigma_k @ M
        f32x4 mp[2];
        mp[0] = 0.f; mp[1] = 0.f;
        #pragma unroll
        for (int st = 0; st < 2; ++st)
            #pragma unroll
            for (int ks = 0; ks < 4; ++ks) {
                short8 a = *(short8*)&skR[(16 * st + m) * SKR_LD + 32 * ks + 8 * g];
                mp[st] = __builtin_amdgcn_mfma_f32_16x16x32_bf16(a, Bf[ks], mp[st], 0, 0, 0);
            }

        // delta_v -> dvT[e][s] (intra-wave rows: no barrier needed)
        #pragma unroll
        for (int st = 0; st < 2; ++st) {
            float dv[4];
            #pragma unroll
            for (int r = 0; r < 4; ++r)
                dv[r] = vv[st][r] - mp[st][r] / normsh[16 * st + 4 * g + r];
            *(u64*)&dvT[(16 * w + m) * DV_LD + 16 * st + 4 * g] =
                pack4(dv[0], dv[1], dv[2], dv[3]);
        }
        asm volatile("" ::: "memory");  // fence: dvT write -> read

        short8 bfr = *(short8*)&dvT[(16 * w + m) * DV_LD + 8 * g];

        // MFMA2: acc += sigma^T @ delta_v
        #pragma unroll
        for (int dt = 0; dt < 8; ++dt) {
            short8 a2 = *(short8*)&skT[(16 * dt + m) * SKT_LD + 8 * g];
            acc[dt] = __builtin_amdgcn_mfma_f32_16x16x32_bf16(a2, bfr, acc[dt], 0, 0, 0);
        }

        __syncthreads();   // all reads of skR/skT done

        if (b + 1 < NB) {
            STAGE(kr);     // write skR/skT/normsh for batch b+1
            if (b + 2 < NB) {
                #pragma unroll
                for (int i = 0; i < 4; ++i)
                    kr[i] = *(const float2*)&Kb[(size_t)(sbat + 64 + 4 * w + i) * D + 2 * c2];
            }
        }
        __syncthreads();   // stage visible
    }

    // write pM partial
    float* pMb = pM + ((size_t)bh * NCH + ch) * (D * D);
    #pragma unroll
    for (int dt = 0; dt < 8; ++dt)
        #pragma unroll
        for (int r = 0; r < 4; ++r)
            pMb[(size_t)(16 * dt + 4 * g + r) * D + 16 * w + m] = acc[dt][r];

    // z partial: reduce the 8 wave-row-groups via LDS aliased on skR
    float* zsc = (float*)skR;   // [8][128]
    zsc[w * 128 + 2 * c2]     = zacc0;
    zsc[w * 128 + 2 * c2 + 1] = zacc1;
    __syncthreads();
    if (t < 128) {
        float a = 0.f;
        #pragma unroll
        for (int r = 0; r < 8; ++r) a += zsc[r * 128 + t];
        pz[((size_t)bh * NCH + ch) * D + t] = a;
    }
}

// ---------------------------------------------------------------------------
// Reduce: M_new = M + sum_ch pM ; z_new = z + sum_ch pz
// ---------------------------------------------------------------------------
__global__ void k_reduce(const float* __restrict__ M, const float* __restrict__ z,
                         const float* __restrict__ pM, const float* __restrict__ pz,
                         float* __restrict__ Mnew, float* __restrict__ znew, int NCH)
{
    const int bh = blockIdx.x, sl = blockIdx.y, t = threadIdx.x;
    const size_t baseM = (size_t)bh * D * D;
    for (int i = sl * 2048 + t; i < (sl + 1) * 2048; i += 256) {
        float a = M[baseM + i];
        for (int c = 0; c < NCH; ++c) a += pM[((size_t)bh * NCH + c) * (D * D) + i];
        Mnew[baseM + i] = a;
    }
    if (sl == 0 && t < D) {
        float a = z[(size_t)bh * D + t];
        for (int c = 0; c < NCH; ++c) a += pz[((size_t)bh * NCH + c) * D + t];
        znew[(size_t)bh * D + t] = a;
    }
}

// ---------------------------------------------------------------------------
// Retrieve: out = (sigma_q @ M_new) / (sigma_q @ z_new + eps)
// (unchanged — proven correct, near memory floor)
// ---------------------------------------------------------------------------
__global__ __launch_bounds__(256, 2)
void k_retrieve(const float* __restrict__ query, const float* __restrict__ Mnew,
                const float* __restrict__ znew, float* __restrict__ out, int S)
{
    __shared__ alignas(16) ushort_t sqR[2][32 * SKR_LD];
    __shared__ float normsh[2][32];

    const int t  = threadIdx.x;
    const int bh = blockIdx.x, ch = blockIdx.y, NCH = gridDim.y;
    const int SC = S / NCH;
    const int NB = SC / 32;
    const int s0g = ch * SC;

    const int w = t >> 6, g = (t >> 4) & 3, m = t & 15;
    const int sb = t >> 5, db = t & 31;

    const float* Qb = query + (size_t)bh * S * D;
    const float* Mb = Mnew + (size_t)bh * D * D;
    const float* zb = znew + (size_t)bh * D;
    float*       Ob = out + (size_t)bh * S * D;

    float zr[4];
    #pragma unroll
    for (int j = 0; j < 4; ++j) zr[j] = zb[4 * db + j];

    short8 Bf[4][2];
    #pragma unroll
    for (int ks = 0; ks < 4; ++ks)
        #pragma unroll
        for (int p = 0; p < 2; ++p) {
            short8 f;
            #pragma unroll
            for (int j = 0; j < 8; ++j)
                f[j] = (short)bf16rne(Mb[(size_t)(32 * ks + 8 * g + j) * D + 16 * (2 * w + p) + m]);
            Bf[ks][p] = f;
        }

    auto STAGE_PROC = [&](const float4* qreg, int bu) {
        float sv[4][4];
        #pragma unroll
        for (int js = 0; js < 4; ++js) {
            sv[js][0] = elu1(qreg[js].x); sv[js][1] = elu1(qreg[js].y);
            sv[js][2] = elu1(qreg[js].z); sv[js][3] = elu1(qreg[js].w);
        }
        #pragma unroll
        for (int js = 0; js < 4; ++js)
            *(u64*)&sqR[bu][(4 * sb + js) * SKR_LD + 4 * db] =
                pack4(sv[js][0], sv[js][1], sv[js][2], sv[js][3]);
        float np[4];
        #pragma unroll
        for (int js = 0; js < 4; ++js)
            np[js] = sv[js][0] * zr[0] + sv[js][1] * zr[1] +
                     sv[js][2] * zr[2] + sv[js][3] * zr[3];
        #pragma unroll
        for (int mask = 16; mask >= 1; mask >>= 1) {
            np[0] += __shfl_xor(np[0], mask, 64);
            np[1] += __shfl_xor(np[1], mask, 64);
            np[2] += __shfl_xor(np[2], mask, 64);
            np[3] += __shfl_xor(np[3], mask, 64);
        }
        if (db < 4) {
            float v = db == 0 ? np[0] : db == 1 ? np[1] : db == 2 ? np[2] : np[3];
            normsh[bu][4 * sb + db] = v + EPS;
        }
    };

    {
        float4 qreg[4];
        #pragma unroll
        for (int js = 0; js < 4; ++js)
            qreg[js] = *(const float4*)&Qb[(size_t)(s0g + 4 * sb + js) * D + 4 * db];
        STAGE_PROC(qreg, 0);
    }
    __syncthreads();

    for (int b = 0; b < NB; ++b) {
        const int bu = b & 1;
        float4 qreg[4];
        if (b + 1 < NB) {
            #pragma unroll
            for (int js = 0; js < 4; ++js)
                qreg[js] = *(const float4*)&Qb[(size_t)(s0g + 32 * (b + 1) + 4 * sb + js) * D + 4 * db];
        }

        f32x4 mp[2][2];
        #pragma unroll
        for (int st = 0; st < 2; ++st)
            #pragma unroll
            for (int p = 0; p < 2; ++p) mp[st][p] = 0.f;
        #pragma unroll
        for (int st = 0; st < 2; ++st)
            #pragma unroll
            for (int ks = 0; ks < 4; ++ks) {
                short8 a = *(short8*)&sqR[bu][(16 * st + m) * SKR_LD + 32 * ks + 8 * g];
                #pragma unroll
                for (int p = 0; p < 2; ++p)
                    mp[st][p] = __builtin_amdgcn_mfma_f32_16x16x32_bf16(a, Bf[ks][p], mp[st][p], 0, 0, 0);
            }

        #pragma unroll
        for (int st = 0; st < 2; ++st)
            #pragma unroll
            for (int r = 0; r < 4; ++r) {
                float rn = 1.f / normsh[bu][16 * st + 4 * g + r];
                #pragma unroll
                for (int p = 0; p < 2; ++p)
                    Ob[(size_t)(s0g + 32 * b + 16 * st + 4 * g + r) * D + 16 * (2 * w + p) + m] =
                        mp[st][p][r] * rn;
            }

        if (b + 1 < NB) STAGE_PROC(qreg, (b + 1) & 1);
        __syncthreads();
    }
}

// ---------------------------------------------------------------------------
extern "C" void kernel_launch(void* const* d_in, const int* in_sizes, int n_in,
                              void* d_out, int out_size, void* d_ws, size_t ws_size,
                              hipStream_t stream)
{
    const float* q = (const float*)d_in[0];
    const float* k = (const float*)d_in[1];
    const float* v = (const float*)d_in[2];
    const float* M = (const float*)d_in[3];
    const float* z = (const float*)d_in[4];

    const int BH = in_sizes[3] / (D * D);
    const int S  = in_sizes[0] / (BH * D);

    float* out  = (float*)d_out;
    float* Mnew = out + (size_t)BH * S * D;
    float* znew = Mnew + (size_t)BH * D * D;

    int NCH = 16;
    const size_t per_set = (size_t)BH * (D * D + D) * sizeof(float);
    while (NCH > 1 && (size_t)NCH * per_set > ws_size) NCH >>= 1;

    float* pM;
    float* pz;
    if ((size_t)NCH * per_set <= ws_size) {
        pM = (float*)d_ws;
        pz = pM + (size_t)NCH * BH * D * D;
    } else {
        NCH = 1;
        pM = Mnew;
        pz = znew;
    }

    dim3 gridA(BH, NCH);
    k_update<<<gridA, 512, 0, stream>>>(k, v, M, z, pM, pz, S);
    dim3 gridB(BH, 8);
    k_reduce<<<gridB, 256, 0, stream>>>(M, z, pM, pz, Mnew, znew, NCH);
    dim3 gridC(BH, 8);
    k_retrieve<<<gridC, 256, 0, stream>>>(q, Mnew, znew, out, S);
}

// Round 6
// 180.051 us; speedup vs baseline: 2.5623x; 2.5623x over previous
//
#include <hip/hip_runtime.h>
#include <math.h>

#define D 128
#define EPS 1e-6f
#define SKR_LD 136            // shorts per row, row-major sigma [32][D]
#define SKT_LD 40             // shorts per row, transposed sigma [D][32]
#define DV_LD  40             // shorts per row, dvT [D][32]
#define SKR_SZ (32 * SKR_LD)  // 4352 shorts (8704 B)
#define SKT_SZ (128 * SKT_LD) // 5120 shorts (10240 B)

typedef __attribute__((ext_vector_type(8))) short short8;
typedef __attribute__((ext_vector_type(4))) float f32x4;
typedef unsigned short ushort_t;
typedef unsigned long long u64;

__device__ __forceinline__ float elu1(float x) {
    float e = __expf(fminf(x, 0.f));
    return x > 0.f ? x + 1.f : e;
}
__device__ __forceinline__ unsigned short bf16rne(float f) {
    unsigned u = __builtin_bit_cast(unsigned, f);
    u += 0x7FFFu + ((u >> 16) & 1u);
    return (unsigned short)(u >> 16);
}
__device__ __forceinline__ u64 pack4(float a, float b, float c, float d) {
    return (u64)bf16rne(a) | ((u64)bf16rne(b) << 16) |
           ((u64)bf16rne(c) << 32) | ((u64)bf16rne(d) << 48);
}

// ---------------------------------------------------------------------------
// Update: per (bh, chunk): pM = sigma_k^T @ (V - (sigma_k@M)/(sigma_k@z+eps)),
// pz = sum_s sigma_k.  512 threads = 8 waves; wave w owns e-tile w.
// Single-buffered skR/skT (29.7 KB LDS -> 4 blocks/CU with 1024-block grid),
// 2 barriers per 32-row batch.  Norm via wave shuffle-reduce during STAGE.
// __launch_bounds__(512,4): round 4-proven codegen (60 VGPR, no spill).
// (512,6) in round 5 caused VGPR=40 + 860 MB scratch spill traffic -> 3.5x
// slowdown; do not raise the second arg.
// ---------------------------------------------------------------------------
__global__ __launch_bounds__(512, 4)
void k_update(const float* __restrict__ key, const float* __restrict__ value,
              const float* __restrict__ M, const float* __restrict__ z,
              float* __restrict__ pM, float* __restrict__ pz, int S)
{
    __shared__ alignas(16) ushort_t skR[SKR_SZ];
    __shared__ alignas(16) ushort_t skT[SKT_SZ];
    __shared__ alignas(16) ushort_t dvT[128 * DV_LD];
    __shared__ float normsh[32];

    const int t  = threadIdx.x;
    const int bh = blockIdx.x, ch = blockIdx.y, NCH = gridDim.y;
    const int SC = S / NCH, NB = SC / 32, s0g = ch * SC;

    const int w = t >> 6, g = (t >> 4) & 3, m = t & 15;  // compute roles
    const int c2 = t & 63;                               // stage: rows 4w..4w+3, cols 2c2,2c2+1

    const float* Kb = key   + (size_t)bh * S * D;
    const float* Vb = value + (size_t)bh * S * D;
    const float* Mb = M + (size_t)bh * D * D;
    const float* zb = z + (size_t)bh * D;

    // z (fp32, stage cols) for the shuffle-norm
    const float zr0 = zb[2 * c2], zr1 = zb[2 * c2 + 1];

    // M B-frags in registers (this wave's e-tile)
    short8 Bf[4];
    #pragma unroll
    for (int ks = 0; ks < 4; ++ks) {
        short8 f;
        #pragma unroll
        for (int j = 0; j < 8; ++j)
            f[j] = (short)bf16rne(Mb[(size_t)(32 * ks + 8 * g + j) * D + 16 * w + m]);
        Bf[ks] = f;
    }

    f32x4 acc[8];
    #pragma unroll
    for (int dt = 0; dt < 8; ++dt) acc[dt] = 0.f;
    float zacc0 = 0.f, zacc1 = 0.f;

    // stage: elu(K rows) -> skR (row-major) + skT (transposed); fp32 norm; z acc
    auto STAGE = [&](const float2* kr) {
        float sv0[4], sv1[4];
        #pragma unroll
        for (int i = 0; i < 4; ++i) { sv0[i] = elu1(kr[i].x); sv1[i] = elu1(kr[i].y); }
        #pragma unroll
        for (int i = 0; i < 4; ++i)
            *(unsigned*)&skR[(4 * w + i) * SKR_LD + 2 * c2] =
                (unsigned)bf16rne(sv0[i]) | ((unsigned)bf16rne(sv1[i]) << 16);
        *(u64*)&skT[(2 * c2) * SKT_LD + 4 * w]     = pack4(sv0[0], sv0[1], sv0[2], sv0[3]);
        *(u64*)&skT[(2 * c2 + 1) * SKT_LD + 4 * w] = pack4(sv1[0], sv1[1], sv1[2], sv1[3]);
        float p[4];
        #pragma unroll
        for (int i = 0; i < 4; ++i) {
            p[i] = sv0[i] * zr0 + sv1[i] * zr1;
            zacc0 += sv0[i]; zacc1 += sv1[i];
        }
        #pragma unroll
        for (int mask = 32; mask >= 1; mask >>= 1) {
            p[0] += __shfl_xor(p[0], mask, 64);
            p[1] += __shfl_xor(p[1], mask, 64);
            p[2] += __shfl_xor(p[2], mask, 64);
            p[3] += __shfl_xor(p[3], mask, 64);
        }
        int l = t & 63;
        if (l < 4) {
            float pv = l == 0 ? p[0] : l == 1 ? p[1] : l == 2 ? p[2] : p[3];
            normsh[4 * w + l] = pv + EPS;
        }
    };

    // prologue: stage batch 0; prefetch K(1), V(0)
    float2 kr[4];
    #pragma unroll
    for (int i = 0; i < 4; ++i)
        kr[i] = *(const float2*)&Kb[(size_t)(s0g + 4 * w + i) * D + 2 * c2];
    STAGE(kr);
    if (NB > 1) {
        #pragma unroll
        for (int i = 0; i < 4; ++i)
            kr[i] = *(const float2*)&Kb[(size_t)(s0g + 32 + 4 * w + i) * D + 2 * c2];
    }
    float vn[2][4];
    #pragma unroll
    for (int st = 0; st < 2; ++st)
        #pragma unroll
        for (int r = 0; r < 4; ++r)
            vn[st][r] = Vb[(size_t)(s0g + 16 * st + 4 * g + r) * D + 16 * w + m];
    __syncthreads();

    for (int b = 0; b < NB; ++b) {
        const int sbat = s0g + 32 * b;

        // current V from prefetch regs
        float vv[2][4];
        #pragma unroll
        for (int st = 0; st < 2; ++st)
            #pragma unroll
            for (int r = 0; r < 4; ++r) vv[st][r] = vn[st][r];

        // issue V(b+1) prefetch
        if (b + 1 < NB) {
            #pragma unroll
            for (int st = 0; st < 2; ++st)
                #pragma unroll
                for (int r = 0; r < 4; ++r)
                    vn[st][r] = Vb[(size_t)(sbat + 32 + 16 * st + 4 * g + r) * D + 16 * w + m];
        }

        // MFMA1: mem_pred = sigma_k @ M
        f32x4 mp[2];
        mp[0] = 0.f; mp[1] = 0.f;
        #pragma unroll
        for (int st = 0; st < 2; ++st)
            #pragma unroll
            for (int ks = 0; ks < 4; ++ks) {
                short8 a = *(short8*)&skR[(16 * st + m) * SKR_LD + 32 * ks + 8 * g];
                mp[st] = __builtin_amdgcn_mfma_f32_16x16x32_bf16(a, Bf[ks], mp[st], 0, 0, 0);
            }

        // delta_v -> dvT[e][s] (intra-wave rows: no barrier needed)
        #pragma unroll
        for (int st = 0; st < 2; ++st) {
            float dv[4];
            #pragma unroll
            for (int r = 0; r < 4; ++r)
                dv[r] = vv[st][r] - mp[st][r] / normsh[16 * st + 4 * g + r];
            *(u64*)&dvT[(16 * w + m) * DV_LD + 16 * st + 4 * g] =
                pack4(dv[0], dv[1], dv[2], dv[3]);
        }
        asm volatile("" ::: "memory");  // fence: dvT write -> read

        short8 bfr = *(short8*)&dvT[(16 * w + m) * DV_LD + 8 * g];

        // MFMA2: acc += sigma^T @ delta_v
        #pragma unroll
        for (int dt = 0; dt < 8; ++dt) {
            short8 a2 = *(short8*)&skT[(16 * dt + m) * SKT_LD + 8 * g];
            acc[dt] = __builtin_amdgcn_mfma_f32_16x16x32_bf16(a2, bfr, acc[dt], 0, 0, 0);
        }

        __syncthreads();   // all reads of skR/skT done

        if (b + 1 < NB) {
            STAGE(kr);     // write skR/skT/normsh for batch b+1
            if (b + 2 < NB) {
                #pragma unroll
                for (int i = 0; i < 4; ++i)
                    kr[i] = *(const float2*)&Kb[(size_t)(sbat + 64 + 4 * w + i) * D + 2 * c2];
            }
        }
        __syncthreads();   // stage visible
    }

    // write pM partial
    float* pMb = pM + ((size_t)bh * NCH + ch) * (D * D);
    #pragma unroll
    for (int dt = 0; dt < 8; ++dt)
        #pragma unroll
        for (int r = 0; r < 4; ++r)
            pMb[(size_t)(16 * dt + 4 * g + r) * D + 16 * w + m] = acc[dt][r];

    // z partial: reduce the 8 wave-row-groups via LDS aliased on skR
    float* zsc = (float*)skR;   // [8][128]
    zsc[w * 128 + 2 * c2]     = zacc0;
    zsc[w * 128 + 2 * c2 + 1] = zacc1;
    __syncthreads();
    if (t < 128) {
        float a = 0.f;
        #pragma unroll
        for (int r = 0; r < 8; ++r) a += zsc[r * 128 + t];
        pz[((size_t)bh * NCH + ch) * D + t] = a;
    }
}

// ---------------------------------------------------------------------------
// Reduce: M_new = M + sum_ch pM ; z_new = z + sum_ch pz
// ---------------------------------------------------------------------------
__global__ void k_reduce(const float* __restrict__ M, const float* __restrict__ z,
                         const float* __restrict__ pM, const float* __restrict__ pz,
                         float* __restrict__ Mnew, float* __restrict__ znew, int NCH)
{
    const int bh = blockIdx.x, sl = blockIdx.y, t = threadIdx.x;
    const size_t baseM = (size_t)bh * D * D;
    for (int i = sl * 2048 + t; i < (sl + 1) * 2048; i += 256) {
        float a = M[baseM + i];
        for (int c = 0; c < NCH; ++c) a += pM[((size_t)bh * NCH + c) * (D * D) + i];
        Mnew[baseM + i] = a;
    }
    if (sl == 0 && t < D) {
        float a = z[(size_t)bh * D + t];
        for (int c = 0; c < NCH; ++c) a += pz[((size_t)bh * NCH + c) * D + t];
        znew[(size_t)bh * D + t] = a;
    }
}

// ---------------------------------------------------------------------------
// Retrieve: out = (sigma_q @ M_new) / (sigma_q @ z_new + eps)
// (unchanged — proven correct, near memory floor)
// ---------------------------------------------------------------------------
__global__ __launch_bounds__(256, 2)
void k_retrieve(const float* __restrict__ query, const float* __restrict__ Mnew,
                const float* __restrict__ znew, float* __restrict__ out, int S)
{
    __shared__ alignas(16) ushort_t sqR[2][32 * SKR_LD];
    __shared__ float normsh[2][32];

    const int t  = threadIdx.x;
    const int bh = blockIdx.x, ch = blockIdx.y, NCH = gridDim.y;
    const int SC = S / NCH;
    const int NB = SC / 32;
    const int s0g = ch * SC;

    const int w = t >> 6, g = (t >> 4) & 3, m = t & 15;
    const int sb = t >> 5, db = t & 31;

    const float* Qb = query + (size_t)bh * S * D;
    const float* Mb = Mnew + (size_t)bh * D * D;
    const float* zb = znew + (size_t)bh * D;
    float*       Ob = out + (size_t)bh * S * D;

    float zr[4];
    #pragma unroll
    for (int j = 0; j < 4; ++j) zr[j] = zb[4 * db + j];

    short8 Bf[4][2];
    #pragma unroll
    for (int ks = 0; ks < 4; ++ks)
        #pragma unroll
        for (int p = 0; p < 2; ++p) {
            short8 f;
            #pragma unroll
            for (int j = 0; j < 8; ++j)
                f[j] = (short)bf16rne(Mb[(size_t)(32 * ks + 8 * g + j) * D + 16 * (2 * w + p) + m]);
            Bf[ks][p] = f;
        }

    auto STAGE_PROC = [&](const float4* qreg, int bu) {
        float sv[4][4];
        #pragma unroll
        for (int js = 0; js < 4; ++js) {
            sv[js][0] = elu1(qreg[js].x); sv[js][1] = elu1(qreg[js].y);
            sv[js][2] = elu1(qreg[js].z); sv[js][3] = elu1(qreg[js].w);
        }
        #pragma unroll
        for (int js = 0; js < 4; ++js)
            *(u64*)&sqR[bu][(4 * sb + js) * SKR_LD + 4 * db] =
                pack4(sv[js][0], sv[js][1], sv[js][2], sv[js][3]);
        float np[4];
        #pragma unroll
        for (int js = 0; js < 4; ++js)
            np[js] = sv[js][0] * zr[0] + sv[js][1] * zr[1] +
                     sv[js][2] * zr[2] + sv[js][3] * zr[3];
        #pragma unroll
        for (int mask = 16; mask >= 1; mask >>= 1) {
            np[0] += __shfl_xor(np[0], mask, 64);
            np[1] += __shfl_xor(np[1], mask, 64);
            np[2] += __shfl_xor(np[2], mask, 64);
            np[3] += __shfl_xor(np[3], mask, 64);
        }
        if (db < 4) {
            float v = db == 0 ? np[0] : db == 1 ? np[1] : db == 2 ? np[2] : np[3];
            normsh[bu][4 * sb + db] = v + EPS;
        }
    };

    {
        float4 qreg[4];
        #pragma unroll
        for (int js = 0; js < 4; ++js)
            qreg[js] = *(const float4*)&Qb[(size_t)(s0g + 4 * sb + js) * D + 4 * db];
        STAGE_PROC(qreg, 0);
    }
    __syncthreads();

    for (int b = 0; b < NB; ++b) {
        const int bu = b & 1;
        float4 qreg[4];
        if (b + 1 < NB) {
            #pragma unroll
            for (int js = 0; js < 4; ++js)
                qreg[js] = *(const float4*)&Qb[(size_t)(s0g + 32 * (b + 1) + 4 * sb + js) * D + 4 * db];
        }

        f32x4 mp[2][2];
        #pragma unroll
        for (int st = 0; st < 2; ++st)
            #pragma unroll
            for (int p = 0; p < 2; ++p) mp[st][p] = 0.f;
        #pragma unroll
        for (int st = 0; st < 2; ++st)
            #pragma unroll
            for (int ks = 0; ks < 4; ++ks) {
                short8 a = *(short8*)&sqR[bu][(16 * st + m) * SKR_LD + 32 * ks + 8 * g];
                #pragma unroll
                for (int p = 0; p < 2; ++p)
                    mp[st][p] = __builtin_amdgcn_mfma_f32_16x16x32_bf16(a, Bf[ks][p], mp[st][p], 0, 0, 0);
            }

        #pragma unroll
        for (int st = 0; st < 2; ++st)
            #pragma unroll
            for (int r = 0; r < 4; ++r) {
                float rn = 1.f / normsh[bu][16 * st + 4 * g + r];
                #pragma unroll
                for (int p = 0; p < 2; ++p)
                    Ob[(size_t)(s0g + 32 * b + 16 * st + 4 * g + r) * D + 16 * (2 * w + p) + m] =
                        mp[st][p][r] * rn;
            }

        if (b + 1 < NB) STAGE_PROC(qreg, (b + 1) & 1);
        __syncthreads();
    }
}

// ---------------------------------------------------------------------------
extern "C" void kernel_launch(void* const* d_in, const int* in_sizes, int n_in,
                              void* d_out, int out_size, void* d_ws, size_t ws_size,
                              hipStream_t stream)
{
    const float* q = (const float*)d_in[0];
    const float* k = (const float*)d_in[1];
    const float* v = (const float*)d_in[2];
    const float* M = (const float*)d_in[3];
    const float* z = (const float*)d_in[4];

    const int BH = in_sizes[3] / (D * D);
    const int S  = in_sizes[0] / (BH * D);

    float* out  = (float*)d_out;
    float* Mnew = out + (size_t)BH * S * D;
    float* znew = Mnew + (size_t)BH * D * D;

    int NCH = 16;
    const size_t per_set = (size_t)BH * (D * D + D) * sizeof(float);
    while (NCH > 1 && (size_t)NCH * per_set > ws_size) NCH >>= 1;

    float* pM;
    float* pz;
    if ((size_t)NCH * per_set <= ws_size) {
        pM = (float*)d_ws;
        pz = pM + (size_t)NCH * BH * D * D;
    } else {
        NCH = 1;
        pM = Mnew;
        pz = znew;
    }

    dim3 gridA(BH, NCH);
    k_update<<<gridA, 512, 0, stream>>>(k, v, M, z, pM, pz, S);
    dim3 gridB(BH, 8);
    k_reduce<<<gridB, 256, 0, stream>>>(M, z, pM, pz, Mnew, znew, NCH);
    dim3 gridC(BH, 8);
    k_retrieve<<<gridC, 256, 0, stream>>>(q, Mnew, znew, out, S);
}

// Round 7
// 179.776 us; speedup vs baseline: 2.5662x; 1.0015x over previous
//
#include <hip/hip_runtime.h>
#include <math.h>

#define D 128
#define EPS 1e-6f
#define SKR_LD 136            // shorts per row, row-major sigma [32][D]
#define SKT_LD 40             // shorts per row, transposed sigma [D][32]
#define DV_LD  40             // shorts per row, dvT [D][32]
#define SKR_SZ (32 * SKR_LD)  // 4352 shorts (8704 B)
#define SKT_SZ (128 * SKT_LD) // 5120 shorts (10240 B)

typedef __attribute__((ext_vector_type(8))) short short8;
typedef __attribute__((ext_vector_type(4))) float f32x4;
typedef unsigned short ushort_t;
typedef unsigned long long u64;

__device__ __forceinline__ float elu1(float x) {
    float e = __expf(fminf(x, 0.f));
    return x > 0.f ? x + 1.f : e;
}
__device__ __forceinline__ unsigned short bf16rne(float f) {
    unsigned u = __builtin_bit_cast(unsigned, f);
    u += 0x7FFFu + ((u >> 16) & 1u);
    return (unsigned short)(u >> 16);
}
__device__ __forceinline__ u64 pack4(float a, float b, float c, float d) {
    return (u64)bf16rne(a) | ((u64)bf16rne(b) << 16) |
           ((u64)bf16rne(c) << 32) | ((u64)bf16rne(d) << 48);
}

// ---------------------------------------------------------------------------
// Update: per (bh, chunk): pM = sigma_k^T @ (V - (sigma_k@M)/(sigma_k@z+eps)),
// pz = sum_s sigma_k.  512 threads = 8 waves; wave w owns e-tile w.
// Double-buffered skR/skT (48 KB LDS, 3 blocks/CU), ONE barrier per 32-row
// batch, and the barrier is a custom `s_waitcnt lgkmcnt(0); s_barrier` —
// vmcnt is deliberately NOT drained, so K(b+1)/V(b+1) prefetch latency
// spans the whole batch (T4 counted-wait; __syncthreads would drain vmcnt(0)
// every phase and expose ~900cy HBM latency per batch).
// Normalizer via replicated-z MFMA (round-4-proven) — no shuffles, no normsh.
// __launch_bounds__(512,4): round-5 lesson — (512,6) spilled (VGPR 40 +
// 860 MB scratch traffic, 3.5x slower). Do not raise.
// ---------------------------------------------------------------------------
__global__ __launch_bounds__(512, 4)
void k_update(const float* __restrict__ key, const float* __restrict__ value,
              const float* __restrict__ M, const float* __restrict__ z,
              float* __restrict__ pM, float* __restrict__ pz, int S)
{
    __shared__ alignas(16) ushort_t skR[2 * SKR_SZ];
    __shared__ alignas(16) ushort_t skT[2 * SKT_SZ];
    __shared__ alignas(16) ushort_t dvT[128 * DV_LD];

    const int t  = threadIdx.x;
    const int bh = blockIdx.x, ch = blockIdx.y, NCH = gridDim.y;
    const int SC = S / NCH, NB = SC / 32, s0g = ch * SC;

    const int w = t >> 6, g = (t >> 4) & 3, m = t & 15;  // compute roles
    const int c2 = t & 63;                               // stage: rows 4w..4w+3, cols 2c2,2c2+1

    const float* Kb = key   + (size_t)bh * S * D;
    const float* Vb = value + (size_t)bh * S * D;
    const float* Mb = M + (size_t)bh * D * D;
    const float* zb = z + (size_t)bh * D;

    // B-frags in registers: M columns (this wave's e-tile) and replicated z
    short8 Bf[4], zf[4];
    #pragma unroll
    for (int ks = 0; ks < 4; ++ks) {
        short8 f, zfr;
        #pragma unroll
        for (int j = 0; j < 8; ++j) {
            f[j]   = (short)bf16rne(Mb[(size_t)(32 * ks + 8 * g + j) * D + 16 * w + m]);
            zfr[j] = (short)bf16rne(zb[32 * ks + 8 * g + j]);
        }
        Bf[ks] = f; zf[ks] = zfr;
    }

    f32x4 acc[8];
    #pragma unroll
    for (int dt = 0; dt < 8; ++dt) acc[dt] = 0.f;
    float zacc0 = 0.f, zacc1 = 0.f;

    // stage: elu(K rows) -> skR (row-major) + skT (transposed); z partials
    auto STAGE = [&](const float2* kr, int buf) {
        float sv0[4], sv1[4];
        #pragma unroll
        for (int i = 0; i < 4; ++i) { sv0[i] = elu1(kr[i].x); sv1[i] = elu1(kr[i].y); }
        #pragma unroll
        for (int i = 0; i < 4; ++i)
            *(unsigned*)&skR[buf * SKR_SZ + (4 * w + i) * SKR_LD + 2 * c2] =
                (unsigned)bf16rne(sv0[i]) | ((unsigned)bf16rne(sv1[i]) << 16);
        *(u64*)&skT[buf * SKT_SZ + (2 * c2) * SKT_LD + 4 * w]     = pack4(sv0[0], sv0[1], sv0[2], sv0[3]);
        *(u64*)&skT[buf * SKT_SZ + (2 * c2 + 1) * SKT_LD + 4 * w] = pack4(sv1[0], sv1[1], sv1[2], sv1[3]);
        zacc0 += sv0[0] + sv0[1] + sv0[2] + sv0[3];
        zacc1 += sv1[0] + sv1[1] + sv1[2] + sv1[3];
    };

    // prologue: stage batch 0; issue K(1) + V(0) prefetch
    float2 kr[4];
    #pragma unroll
    for (int i = 0; i < 4; ++i)
        kr[i] = *(const float2*)&Kb[(size_t)(s0g + 4 * w + i) * D + 2 * c2];
    STAGE(kr, 0);
    if (NB > 1) {
        #pragma unroll
        for (int i = 0; i < 4; ++i)
            kr[i] = *(const float2*)&Kb[(size_t)(s0g + 32 + 4 * w + i) * D + 2 * c2];
    }
    float vn[2][4];
    #pragma unroll
    for (int st = 0; st < 2; ++st)
        #pragma unroll
        for (int r = 0; r < 4; ++r)
            vn[st][r] = Vb[(size_t)(s0g + 16 * st + 4 * g + r) * D + 16 * w + m];
    __syncthreads();   // one full barrier at start is fine

    for (int b = 0; b < NB; ++b) {
        const int cur = b & 1;
        const int sbat = s0g + 32 * b;

        // consume V(b) prefetch; issue V(b+1)
        float vv[2][4];
        #pragma unroll
        for (int st = 0; st < 2; ++st)
            #pragma unroll
            for (int r = 0; r < 4; ++r) vv[st][r] = vn[st][r];
        if (b + 1 < NB) {
            #pragma unroll
            for (int st = 0; st < 2; ++st)
                #pragma unroll
                for (int r = 0; r < 4; ++r)
                    vn[st][r] = Vb[(size_t)(sbat + 32 + 16 * st + 4 * g + r) * D + 16 * w + m];
        }

        // MFMA1: mem_pred = sigma_k @ M ; norm = sigma_k @ z (replicated)
        f32x4 mp[2], mz[2];
        #pragma unroll
        for (int st = 0; st < 2; ++st) { mp[st] = 0.f; mz[st] = 0.f; }
        #pragma unroll
        for (int st = 0; st < 2; ++st)
            #pragma unroll
            for (int ks = 0; ks < 4; ++ks) {
                short8 a = *(short8*)&skR[cur * SKR_SZ + (16 * st + m) * SKR_LD + 32 * ks + 8 * g];
                mp[st] = __builtin_amdgcn_mfma_f32_16x16x32_bf16(a, Bf[ks], mp[st], 0, 0, 0);
                mz[st] = __builtin_amdgcn_mfma_f32_16x16x32_bf16(a, zf[ks], mz[st], 0, 0, 0);
            }

        // delta_v -> dvT[e][s] (intra-wave rows: wave-private, no barrier)
        #pragma unroll
        for (int st = 0; st < 2; ++st) {
            float dv[4];
            #pragma unroll
            for (int r = 0; r < 4; ++r)
                dv[r] = vv[st][r] - mp[st][r] / (mz[st][r] + EPS);
            *(u64*)&dvT[(16 * w + m) * DV_LD + 16 * st + 4 * g] =
                pack4(dv[0], dv[1], dv[2], dv[3]);
        }
        asm volatile("" ::: "memory");  // fence: dvT write -> read

        short8 bfr = *(short8*)&dvT[(16 * w + m) * DV_LD + 8 * g];

        // MFMA2: acc += sigma^T @ delta_v
        #pragma unroll
        for (int dt = 0; dt < 8; ++dt) {
            short8 a2 = *(short8*)&skT[cur * SKT_SZ + (16 * dt + m) * SKT_LD + 8 * g];
            acc[dt] = __builtin_amdgcn_mfma_f32_16x16x32_bf16(a2, bfr, acc[dt], 0, 0, 0);
        }

        // stage next batch into the other buffer; issue K(b+2)
        if (b + 1 < NB) {
            STAGE(kr, cur ^ 1);            // compiler inserts vmcnt wait for kr here
            if (b + 2 < NB) {
                #pragma unroll
                for (int i = 0; i < 4; ++i)
                    kr[i] = *(const float2*)&Kb[(size_t)(sbat + 64 + 4 * w + i) * D + 2 * c2];
            }
        }

        // lgkm-only barrier: LDS drained, global prefetches stay in flight
        asm volatile("s_waitcnt lgkmcnt(0)\n\ts_barrier" ::: "memory");
    }

    // write pM partial
    float* pMb = pM + ((size_t)bh * NCH + ch) * (D * D);
    #pragma unroll
    for (int dt = 0; dt < 8; ++dt)
        #pragma unroll
        for (int r = 0; r < 4; ++r)
            pMb[(size_t)(16 * dt + 4 * g + r) * D + 16 * w + m] = acc[dt][r];

    // z partial: reduce the 8 wave-row-groups via LDS aliased on skR
    __syncthreads();
    float* zsc = (float*)skR;   // [8][128]
    zsc[w * 128 + 2 * c2]     = zacc0;
    zsc[w * 128 + 2 * c2 + 1] = zacc1;
    __syncthreads();
    if (t < 128) {
        float a = 0.f;
        #pragma unroll
        for (int r = 0; r < 8; ++r) a += zsc[r * 128 + t];
        pz[((size_t)bh * NCH + ch) * D + t] = a;
    }
}

// ---------------------------------------------------------------------------
// Reduce: M_new = M + sum_ch pM ; z_new = z + sum_ch pz
// ---------------------------------------------------------------------------
__global__ void k_reduce(const float* __restrict__ M, const float* __restrict__ z,
                         const float* __restrict__ pM, const float* __restrict__ pz,
                         float* __restrict__ Mnew, float* __restrict__ znew, int NCH)
{
    const int bh = blockIdx.x, sl = blockIdx.y, t = threadIdx.x;
    const size_t baseM = (size_t)bh * D * D;
    for (int i = sl * 2048 + t; i < (sl + 1) * 2048; i += 256) {
        float a = M[baseM + i];
        for (int c = 0; c < NCH; ++c) a += pM[((size_t)bh * NCH + c) * (D * D) + i];
        Mnew[baseM + i] = a;
    }
    if (sl == 0 && t < D) {
        float a = z[(size_t)bh * D + t];
        for (int c = 0; c < NCH; ++c) a += pz[((size_t)bh * NCH + c) * D + t];
        znew[(size_t)bh * D + t] = a;
    }
}

// ---------------------------------------------------------------------------
// Retrieve: out = (sigma_q @ M_new) / (sigma_q @ z_new + eps)
// (unchanged — proven correct, near memory floor)
// ---------------------------------------------------------------------------
__global__ __launch_bounds__(256, 2)
void k_retrieve(const float* __restrict__ query, const float* __restrict__ Mnew,
                const float* __restrict__ znew, float* __restrict__ out, int S)
{
    __shared__ alignas(16) ushort_t sqR[2][32 * SKR_LD];
    __shared__ float normsh[2][32];

    const int t  = threadIdx.x;
    const int bh = blockIdx.x, ch = blockIdx.y, NCH = gridDim.y;
    const int SC = S / NCH;
    const int NB = SC / 32;
    const int s0g = ch * SC;

    const int w = t >> 6, g = (t >> 4) & 3, m = t & 15;
    const int sb = t >> 5, db = t & 31;

    const float* Qb = query + (size_t)bh * S * D;
    const float* Mb = Mnew + (size_t)bh * D * D;
    const float* zb = znew + (size_t)bh * D;
    float*       Ob = out + (size_t)bh * S * D;

    float zr[4];
    #pragma unroll
    for (int j = 0; j < 4; ++j) zr[j] = zb[4 * db + j];

    short8 Bf[4][2];
    #pragma unroll
    for (int ks = 0; ks < 4; ++ks)
        #pragma unroll
        for (int p = 0; p < 2; ++p) {
            short8 f;
            #pragma unroll
            for (int j = 0; j < 8; ++j)
                f[j] = (short)bf16rne(Mb[(size_t)(32 * ks + 8 * g + j) * D + 16 * (2 * w + p) + m]);
            Bf[ks][p] = f;
        }

    auto STAGE_PROC = [&](const float4* qreg, int bu) {
        float sv[4][4];
        #pragma unroll
        for (int js = 0; js < 4; ++js) {
            sv[js][0] = elu1(qreg[js].x); sv[js][1] = elu1(qreg[js].y);
            sv[js][2] = elu1(qreg[js].z); sv[js][3] = elu1(qreg[js].w);
        }
        #pragma unroll
        for (int js = 0; js < 4; ++js)
            *(u64*)&sqR[bu][(4 * sb + js) * SKR_LD + 4 * db] =
                pack4(sv[js][0], sv[js][1], sv[js][2], sv[js][3]);
        float np[4];
        #pragma unroll
        for (int js = 0; js < 4; ++js)
            np[js] = sv[js][0] * zr[0] + sv[js][1] * zr[1] +
                     sv[js][2] * zr[2] + sv[js][3] * zr[3];
        #pragma unroll
        for (int mask = 16; mask >= 1; mask >>= 1) {
            np[0] += __shfl_xor(np[0], mask, 64);
            np[1] += __shfl_xor(np[1], mask, 64);
            np[2] += __shfl_xor(np[2], mask, 64);
            np[3] += __shfl_xor(np[3], mask, 64);
        }
        if (db < 4) {
            float v = db == 0 ? np[0] : db == 1 ? np[1] : db == 2 ? np[2] : np[3];
            normsh[bu][4 * sb + db] = v + EPS;
        }
    };

    {
        float4 qreg[4];
        #pragma unroll
        for (int js = 0; js < 4; ++js)
            qreg[js] = *(const float4*)&Qb[(size_t)(s0g + 4 * sb + js) * D + 4 * db];
        STAGE_PROC(qreg, 0);
    }
    __syncthreads();

    for (int b = 0; b < NB; ++b) {
        const int bu = b & 1;
        float4 qreg[4];
        if (b + 1 < NB) {
            #pragma unroll
            for (int js = 0; js < 4; ++js)
                qreg[js] = *(const float4*)&Qb[(size_t)(s0g + 32 * (b + 1) + 4 * sb + js) * D + 4 * db];
        }

        f32x4 mp[2][2];
        #pragma unroll
        for (int st = 0; st < 2; ++st)
            #pragma unroll
            for (int p = 0; p < 2; ++p) mp[st][p] = 0.f;
        #pragma unroll
        for (int st = 0; st < 2; ++st)
            #pragma unroll
            for (int ks = 0; ks < 4; ++ks) {
                short8 a = *(short8*)&sqR[bu][(16 * st + m) * SKR_LD + 32 * ks + 8 * g];
                #pragma unroll
                for (int p = 0; p < 2; ++p)
                    mp[st][p] = __builtin_amdgcn_mfma_f32_16x16x32_bf16(a, Bf[ks][p], mp[st][p], 0, 0, 0);
            }

        #pragma unroll
        for (int st = 0; st < 2; ++st)
            #pragma unroll
            for (int r = 0; r < 4; ++r) {
                float rn = 1.f / normsh[bu][16 * st + 4 * g + r];
                #pragma unroll
                for (int p = 0; p < 2; ++p)
                    Ob[(size_t)(s0g + 32 * b + 16 * st + 4 * g + r) * D + 16 * (2 * w + p) + m] =
                        mp[st][p][r] * rn;
            }

        if (b + 1 < NB) STAGE_PROC(qreg, (b + 1) & 1);
        __syncthreads();
    }
}

// ---------------------------------------------------------------------------
extern "C" void kernel_launch(void* const* d_in, const int* in_sizes, int n_in,
                              void* d_out, int out_size, void* d_ws, size_t ws_size,
                              hipStream_t stream)
{
    const float* q = (const float*)d_in[0];
    const float* k = (const float*)d_in[1];
    const float* v = (const float*)d_in[2];
    const float* M = (const float*)d_in[3];
    const float* z = (const float*)d_in[4];

    const int BH = in_sizes[3] / (D * D);
    const int S  = in_sizes[0] / (BH * D);

    float* out  = (float*)d_out;
    float* Mnew = out + (size_t)BH * S * D;
    float* znew = Mnew + (size_t)BH * D * D;

    int NCH = 16;
    const size_t per_set = (size_t)BH * (D * D + D) * sizeof(float);
    while (NCH > 1 && (size_t)NCH * per_set > ws_size) NCH >>= 1;

    float* pM;
    float* pz;
    if ((size_t)NCH * per_set <= ws_size) {
        pM = (float*)d_ws;
        pz = pM + (size_t)NCH * BH * D * D;
    } else {
        NCH = 1;
        pM = Mnew;
        pz = znew;
    }

    dim3 gridA(BH, NCH);
    k_update<<<gridA, 512, 0, stream>>>(k, v, M, z, pM, pz, S);
    dim3 gridB(BH, 8);
    k_reduce<<<gridB, 256, 0, stream>>>(M, z, pM, pz, Mnew, znew, NCH);
    dim3 gridC(BH, 8);
    k_retrieve<<<gridC, 256, 0, stream>>>(q, Mnew, znew, out, S);
}

// Round 8
// 177.711 us; speedup vs baseline: 2.5961x; 1.0116x over previous
//
#include <hip/hip_runtime.h>
#include <math.h>

#define D 128
#define EPS 1e-6f
#define TLD 40                 // shorts per row of sT/vT (80B rows, 16B units)
#define TSZ (128 * TLD)        // 5120 shorts per buffer
#define SKR_LD 136             // retrieve kernel (unchanged, proven)

typedef __attribute__((ext_vector_type(8))) short short8;
typedef __attribute__((ext_vector_type(4))) float f32x4;
typedef unsigned short ushort_t;
typedef unsigned long long u64;

__device__ __forceinline__ float elu1(float x) {
    float e = __expf(fminf(x, 0.f));
    return x > 0.f ? x + 1.f : e;
}
__device__ __forceinline__ unsigned short bf16rne(float f) {
    unsigned u = __builtin_bit_cast(unsigned, f);
    u += 0x7FFFu + ((u >> 16) & 1u);
    return (unsigned short)(u >> 16);
}
__device__ __forceinline__ float bf2f(unsigned short h) {
    unsigned u = (unsigned)h << 16;
    return __builtin_bit_cast(float, u);
}
__device__ __forceinline__ u64 pack4(float a, float b, float c, float d) {
    return (u64)bf16rne(a) | ((u64)bf16rne(b) << 16) |
           ((u64)bf16rne(c) << 32) | ((u64)bf16rne(d) << 48);
}
// swizzled short-index of 16B unit u within row f of a [128][TLD] tile.
// XOR of (f&3)^((f>>2)&3) spreads the former 8-way-conflicted A-frag reads
// (20m+4g mod 32 pattern) across all banks; write side uses the same
// involution so store/load agree (rule 21: both-sides-or-neither).
__device__ __forceinline__ int swzs(int f, int u) {
    return TLD * f + 8 * (u ^ (f & 3) ^ ((f >> 2) & 3));
}

// ---------------------------------------------------------------------------
// Update (reformulated): per (bh,chunk) accumulate
//   pP = sigma^T V      pG = sigma^T diag(1/(sigma.z+eps)) sigma     pz = sum sigma
// M_new = M + pP_tot - pG_tot * M is computed later (k_sum + k_gm).
// Two independent GEMMs sharing A-frags (sigma^T) -> no serial chain per batch.
// 512 thr = 8 waves; wave w owns e/f-tile w (16 cols) of BOTH P and G.
// One lgkm-only barrier per 32-row batch; K/V prefetched in regs.
// ---------------------------------------------------------------------------
__global__ __launch_bounds__(512, 4)
void k_update(const float* __restrict__ key, const float* __restrict__ value,
              const float* __restrict__ z,
              float* __restrict__ pP, float* __restrict__ pG,
              float* __restrict__ pz, int S)
{
    __shared__ alignas(16) ushort_t sT[2 * TSZ];   // sigma^T [128 d][32 s] bf16, dbuf
    __shared__ alignas(16) ushort_t vT[2 * TSZ];   // V^T     [128 e][32 s] bf16, dbuf
    __shared__ float nrm[2][32];                   // 1/(sigma.z+eps), dbuf

    const int t  = threadIdx.x;
    const int bh = blockIdx.x, ch = blockIdx.y, NCH = gridDim.y;
    const int SC = S / NCH, NB = SC / 32, s0g = ch * SC;

    const int w = t >> 6, g = (t >> 4) & 3, m = t & 15;  // compute roles
    const int c2 = t & 63;                               // stage: s-rows 4w..4w+3, d-cols {2c2,2c2+1}

    const float* Kb = key   + (size_t)bh * S * D;
    const float* Vb = value + (size_t)bh * S * D;
    const float* zb = z + (size_t)bh * D;

    const float2 zr = *(const float2*)&zb[2 * c2];

    f32x4 accP[8], accG[8];
    #pragma unroll
    for (int dt = 0; dt < 8; ++dt) { accP[dt] = 0.f; accG[dt] = 0.f; }
    float zacc0 = 0.f, zacc1 = 0.f;

    // stage: elu(K) -> sT, V -> vT (both transposed+swizzled); shuffle-norm
    auto STAGE = [&](const float2* kr, const float2* vr, int buf) {
        float sv0[4], sv1[4];
        #pragma unroll
        for (int i = 0; i < 4; ++i) { sv0[i] = elu1(kr[i].x); sv1[i] = elu1(kr[i].y); }
        const int u = w >> 1, h4 = 4 * (w & 1);
        *(u64*)&sT[buf * TSZ + swzs(2 * c2,     u) + h4] = pack4(sv0[0], sv0[1], sv0[2], sv0[3]);
        *(u64*)&sT[buf * TSZ + swzs(2 * c2 + 1, u) + h4] = pack4(sv1[0], sv1[1], sv1[2], sv1[3]);
        *(u64*)&vT[buf * TSZ + swzs(2 * c2,     u) + h4] = pack4(vr[0].x, vr[1].x, vr[2].x, vr[3].x);
        *(u64*)&vT[buf * TSZ + swzs(2 * c2 + 1, u) + h4] = pack4(vr[0].y, vr[1].y, vr[2].y, vr[3].y);
        float p[4];
        #pragma unroll
        for (int i = 0; i < 4; ++i) {
            p[i] = sv0[i] * zr.x + sv1[i] * zr.y;
            zacc0 += sv0[i]; zacc1 += sv1[i];
        }
        #pragma unroll
        for (int mask = 32; mask >= 1; mask >>= 1) {
            p[0] += __shfl_xor(p[0], mask, 64);
            p[1] += __shfl_xor(p[1], mask, 64);
            p[2] += __shfl_xor(p[2], mask, 64);
            p[3] += __shfl_xor(p[3], mask, 64);
        }
        int l = t & 63;
        if (l < 4) {
            float pv = l == 0 ? p[0] : l == 1 ? p[1] : l == 2 ? p[2] : p[3];
            nrm[buf][4 * w + l] = 1.f / (pv + EPS);
        }
    };

    // prologue: load+stage batch 0; prefetch batch 1
    float2 kr[4], vr[4];
    #pragma unroll
    for (int i = 0; i < 4; ++i) {
        kr[i] = *(const float2*)&Kb[(size_t)(s0g + 4 * w + i) * D + 2 * c2];
        vr[i] = *(const float2*)&Vb[(size_t)(s0g + 4 * w + i) * D + 2 * c2];
    }
    STAGE(kr, vr, 0);
    if (NB > 1) {
        #pragma unroll
        for (int i = 0; i < 4; ++i) {
            kr[i] = *(const float2*)&Kb[(size_t)(s0g + 32 + 4 * w + i) * D + 2 * c2];
            vr[i] = *(const float2*)&Vb[(size_t)(s0g + 32 + 4 * w + i) * D + 2 * c2];
        }
    }
    __syncthreads();

    for (int b = 0; b < NB; ++b) {
        const int cur = b & 1;

        // ---- COMPUTE(b): 16 independent MFMAs, shared A-frags ----
        float rn[8];
        #pragma unroll
        for (int j = 0; j < 8; ++j) rn[j] = nrm[cur][8 * g + j];
        short8 bv = *(short8*)&vT[cur * TSZ + swzs(16 * w + m, g)];
        short8 bs = *(short8*)&sT[cur * TSZ + swzs(16 * w + m, g)];
        short8 bg;
        #pragma unroll
        for (int j = 0; j < 8; ++j) bg[j] = (short)bf16rne(bf2f((unsigned short)bs[j]) * rn[j]);
        #pragma unroll
        for (int dt = 0; dt < 8; ++dt) {
            short8 a = *(short8*)&sT[cur * TSZ + swzs(16 * dt + m, g)];
            accP[dt] = __builtin_amdgcn_mfma_f32_16x16x32_bf16(a, bv, accP[dt], 0, 0, 0);
            accG[dt] = __builtin_amdgcn_mfma_f32_16x16x32_bf16(a, bg, accG[dt], 0, 0, 0);
        }

        // ---- STAGE(b+1) into other buffer; then issue loads for b+2 ----
        if (b + 1 < NB) {
            STAGE(kr, vr, cur ^ 1);
            if (b + 2 < NB) {
                const int snx = s0g + 32 * (b + 2);
                #pragma unroll
                for (int i = 0; i < 4; ++i) {
                    kr[i] = *(const float2*)&Kb[(size_t)(snx + 4 * w + i) * D + 2 * c2];
                    vr[i] = *(const float2*)&Vb[(size_t)(snx + 4 * w + i) * D + 2 * c2];
                }
            }
        }
        // lgkm-only barrier: LDS drained, global prefetches stay in flight
        asm volatile("s_waitcnt lgkmcnt(0)\n\ts_barrier" ::: "memory");
    }

    // write partials (fp32)
    float* pPb = pP + ((size_t)bh * NCH + ch) * (D * D);
    float* pGb = pG + ((size_t)bh * NCH + ch) * (D * D);
    #pragma unroll
    for (int dt = 0; dt < 8; ++dt)
        #pragma unroll
        for (int r = 0; r < 4; ++r) {
            pPb[(size_t)(16 * dt + 4 * g + r) * D + 16 * w + m] = accP[dt][r];
            pGb[(size_t)(16 * dt + 4 * g + r) * D + 16 * w + m] = accG[dt][r];
        }

    // z partial: reduce 8 wave-row-groups via LDS aliased on sT
    __syncthreads();
    float* zsc = (float*)sT;   // [8][128]
    zsc[w * 128 + 2 * c2]     = zacc0;
    zsc[w * 128 + 2 * c2 + 1] = zacc1;
    __syncthreads();
    if (t < 128) {
        float a = 0.f;
        #pragma unroll
        for (int r = 0; r < 8; ++r) a += zsc[r * 128 + t];
        pz[((size_t)bh * NCH + ch) * D + t] = a;
    }
}

// ---------------------------------------------------------------------------
// Sum: Mtmp = M + sum_ch pP ; (gh,gl) = split-bf16 of -(sum_ch pG) ;
//      z_new = z + sum_ch pz
// ---------------------------------------------------------------------------
__global__ void k_sum(const float* __restrict__ M, const float* __restrict__ z,
                      const float* __restrict__ pP, const float* __restrict__ pG,
                      const float* __restrict__ pz,
                      float* __restrict__ Mtmp, ushort_t* __restrict__ gh,
                      ushort_t* __restrict__ gl, float* __restrict__ znew, int NCH)
{
    const int bh = blockIdx.x, sl = blockIdx.y, t = threadIdx.x;
    const size_t base = (size_t)bh * D * D;
    for (int i = sl * 2048 + t; i < (sl + 1) * 2048; i += 256) {
        float sp = M[base + i];
        float sg = 0.f;
        for (int c = 0; c < NCH; ++c) {
            sp += pP[((size_t)bh * NCH + c) * (D * D) + i];
            sg += pG[((size_t)bh * NCH + c) * (D * D) + i];
        }
        Mtmp[base + i] = sp;
        float nG = -sg;
        unsigned short hi = bf16rne(nG);
        gh[base + i] = hi;
        gl[base + i] = bf16rne(nG - bf2f(hi));
    }
    if (sl == 0 && t < D) {
        float a = z[(size_t)bh * D + t];
        for (int c = 0; c < NCH; ++c) a += pz[((size_t)bh * NCH + c) * D + t];
        znew[(size_t)bh * D + t] = a;
    }
}

// ---------------------------------------------------------------------------
// GM: M_new = Mtmp + (gh+gl) @ M   (gh/gl hold -G in split bf16)
// 64 blocks x 256 thr; wave w2 covers e-cols 32*w2 + 16*p + m.
// ---------------------------------------------------------------------------
__global__ __launch_bounds__(256)
void k_gm(const float* __restrict__ M, const float* __restrict__ Mtmp,
          const ushort_t* __restrict__ gh, const ushort_t* __restrict__ gl,
          float* __restrict__ Mnew)
{
    const int bh = blockIdx.x, t = threadIdx.x;
    const int w2 = t >> 6, g = (t >> 4) & 3, m = t & 15;
    const float* Mb = M + (size_t)bh * D * D;
    const float* Tb = Mtmp + (size_t)bh * D * D;
    const ushort_t* ghb = gh + (size_t)bh * D * D;
    const ushort_t* glb = gl + (size_t)bh * D * D;
    float* Ob = Mnew + (size_t)bh * D * D;

    f32x4 acc[8][2];
    #pragma unroll
    for (int dt = 0; dt < 8; ++dt)
        #pragma unroll
        for (int p = 0; p < 2; ++p)
            #pragma unroll
            for (int r = 0; r < 4; ++r)
                acc[dt][p][r] = Tb[(size_t)(16 * dt + 4 * g + r) * D + 32 * w2 + 16 * p + m];

    #pragma unroll
    for (int ks = 0; ks < 4; ++ks) {
        short8 bm[2];
        #pragma unroll
        for (int p = 0; p < 2; ++p)
            #pragma unroll
            for (int j = 0; j < 8; ++j)
                bm[p][j] = (short)bf16rne(Mb[(size_t)(32 * ks + 8 * g + j) * D + 32 * w2 + 16 * p + m]);
        #pragma unroll
        for (int dt = 0; dt < 8; ++dt) {
            short8 ah = *(const short8*)&ghb[(size_t)(16 * dt + m) * D + 32 * ks + 8 * g];
            short8 al = *(const short8*)&glb[(size_t)(16 * dt + m) * D + 32 * ks + 8 * g];
            #pragma unroll
            for (int p = 0; p < 2; ++p) {
                acc[dt][p] = __builtin_amdgcn_mfma_f32_16x16x32_bf16(ah, bm[p], acc[dt][p], 0, 0, 0);
                acc[dt][p] = __builtin_amdgcn_mfma_f32_16x16x32_bf16(al, bm[p], acc[dt][p], 0, 0, 0);
            }
        }
    }

    #pragma unroll
    for (int dt = 0; dt < 8; ++dt)
        #pragma unroll
        for (int p = 0; p < 2; ++p)
            #pragma unroll
            for (int r = 0; r < 4; ++r)
                Ob[(size_t)(16 * dt + 4 * g + r) * D + 32 * w2 + 16 * p + m] = acc[dt][p][r];
}

// ---------------------------------------------------------------------------
// Retrieve: out = (sigma_q @ M_new) / (sigma_q @ z_new + eps)
// (unchanged since round 2 — proven correct, near memory floor)
// ---------------------------------------------------------------------------
__global__ __launch_bounds__(256, 2)
void k_retrieve(const float* __restrict__ query, const float* __restrict__ Mnew,
                const float* __restrict__ znew, float* __restrict__ out, int S)
{
    __shared__ alignas(16) ushort_t sqR[2][32 * SKR_LD];
    __shared__ float normsh[2][32];

    const int t  = threadIdx.x;
    const int bh = blockIdx.x, ch = blockIdx.y, NCH = gridDim.y;
    const int SC = S / NCH;
    const int NB = SC / 32;
    const int s0g = ch * SC;

    const int w = t >> 6, g = (t >> 4) & 3, m = t & 15;
    const int sb = t >> 5, db = t & 31;

    const float* Qb = query + (size_t)bh * S * D;
    const float* Mb = Mnew + (size_t)bh * D * D;
    const float* zb = znew + (size_t)bh * D;
    float*       Ob = out + (size_t)bh * S * D;

    float zr[4];
    #pragma unroll
    for (int j = 0; j < 4; ++j) zr[j] = zb[4 * db + j];

    short8 Bf[4][2];
    #pragma unroll
    for (int ks = 0; ks < 4; ++ks)
        #pragma unroll
        for (int p = 0; p < 2; ++p) {
            short8 f;
            #pragma unroll
            for (int j = 0; j < 8; ++j)
                f[j] = (short)bf16rne(Mb[(size_t)(32 * ks + 8 * g + j) * D + 16 * (2 * w + p) + m]);
            Bf[ks][p] = f;
        }

    auto STAGE_PROC = [&](const float4* qreg, int bu) {
        float sv[4][4];
        #pragma unroll
        for (int js = 0; js < 4; ++js) {
            sv[js][0] = elu1(qreg[js].x); sv[js][1] = elu1(qreg[js].y);
            sv[js][2] = elu1(qreg[js].z); sv[js][3] = elu1(qreg[js].w);
        }
        #pragma unroll
        for (int js = 0; js < 4; ++js)
            *(u64*)&sqR[bu][(4 * sb + js) * SKR_LD + 4 * db] =
                pack4(sv[js][0], sv[js][1], sv[js][2], sv[js][3]);
        float np[4];
        #pragma unroll
        for (int js = 0; js < 4; ++js)
            np[js] = sv[js][0] * zr[0] + sv[js][1] * zr[1] +
                     sv[js][2] * zr[2] + sv[js][3] * zr[3];
        #pragma unroll
        for (int mask = 16; mask >= 1; mask >>= 1) {
            np[0] += __shfl_xor(np[0], mask, 64);
            np[1] += __shfl_xor(np[1], mask, 64);
            np[2] += __shfl_xor(np[2], mask, 64);
            np[3] += __shfl_xor(np[3], mask, 64);
        }
        if (db < 4) {
            float v = db == 0 ? np[0] : db == 1 ? np[1] : db == 2 ? np[2] : np[3];
            normsh[bu][4 * sb + db] = v + EPS;
        }
    };

    {
        float4 qreg[4];
        #pragma unroll
        for (int js = 0; js < 4; ++js)
            qreg[js] = *(const float4*)&Qb[(size_t)(s0g + 4 * sb + js) * D + 4 * db];
        STAGE_PROC(qreg, 0);
    }
    __syncthreads();

    for (int b = 0; b < NB; ++b) {
        const int bu = b & 1;
        float4 qreg[4];
        if (b + 1 < NB) {
            #pragma unroll
            for (int js = 0; js < 4; ++js)
                qreg[js] = *(const float4*)&Qb[(size_t)(s0g + 32 * (b + 1) + 4 * sb + js) * D + 4 * db];
        }

        f32x4 mp[2][2];
        #pragma unroll
        for (int st = 0; st < 2; ++st)
            #pragma unroll
            for (int p = 0; p < 2; ++p) mp[st][p] = 0.f;
        #pragma unroll
        for (int st = 0; st < 2; ++st)
            #pragma unroll
            for (int ks = 0; ks < 4; ++ks) {
                short8 a = *(short8*)&sqR[bu][(16 * st + m) * SKR_LD + 32 * ks + 8 * g];
                #pragma unroll
                for (int p = 0; p < 2; ++p)
                    mp[st][p] = __builtin_amdgcn_mfma_f32_16x16x32_bf16(a, Bf[ks][p], mp[st][p], 0, 0, 0);
            }

        #pragma unroll
        for (int st = 0; st < 2; ++st)
            #pragma unroll
            for (int r = 0; r < 4; ++r) {
                float rn = 1.f / normsh[bu][16 * st + 4 * g + r];
                #pragma unroll
                for (int p = 0; p < 2; ++p)
                    Ob[(size_t)(s0g + 32 * b + 16 * st + 4 * g + r) * D + 16 * (2 * w + p) + m] =
                        mp[st][p][r] * rn;
            }

        if (b + 1 < NB) STAGE_PROC(qreg, (b + 1) & 1);
        __syncthreads();
    }
}

// ---------------------------------------------------------------------------
extern "C" void kernel_launch(void* const* d_in, const int* in_sizes, int n_in,
                              void* d_out, int out_size, void* d_ws, size_t ws_size,
                              hipStream_t stream)
{
    const float* q = (const float*)d_in[0];
    const float* k = (const float*)d_in[1];
    const float* v = (const float*)d_in[2];
    const float* M = (const float*)d_in[3];
    const float* z = (const float*)d_in[4];

    const int BH = in_sizes[3] / (D * D);
    const int S  = in_sizes[0] / (BH * D);
    const int NCH = 8;

    float* out  = (float*)d_out;
    float* Mnew = out + (size_t)BH * S * D;
    float* znew = Mnew + (size_t)BH * D * D;

    // Scratch lives in the front of `out` (fully overwritten by k_retrieve
    // afterwards; stream-ordered so k_sum/k_gm read it first). Total
    // 2*NCH*BH*16384 + NCH*BH*128 + 2*BH*16384 floats ~= 19M << BH*S*D = 33.5M.
    float* pP   = out;
    float* pG   = pP + (size_t)NCH * BH * D * D;
    float* pz   = pG + (size_t)NCH * BH * D * D;
    float* Mtmp = pz + (size_t)NCH * BH * D;
    ushort_t* gh = (ushort_t*)(Mtmp + (size_t)BH * D * D);
    ushort_t* gl = gh + (size_t)BH * D * D;

    dim3 gridA(BH, NCH);
    k_update<<<gridA, 512, 0, stream>>>(k, v, z, pP, pG, pz, S);
    dim3 gridB(BH, 8);
    k_sum<<<gridB, 256, 0, stream>>>(M, z, pP, pG, pz, Mtmp, gh, gl, znew, NCH);
    k_gm<<<BH, 256, 0, stream>>>(M, Mtmp, gh, gl, Mnew);
    dim3 gridC(BH, 8);
    k_retrieve<<<gridC, 256, 0, stream>>>(q, Mnew, znew, out, S);
}